// Round 4
// baseline (620.840 us; speedup 1.0000x reference)
//
#include <hip/hip_runtime.h>
#include <math.h>

typedef __attribute__((ext_vector_type(8))) short short8;
typedef __attribute__((ext_vector_type(4))) float f32x4;

#define B_ 16
#define T_ 256
#define I_ 64
#define H_ 128
#define K_ 64
#define U_ 256
#define KC 16
#define NTHR 512

#define OUT_OFF_P (B_*T_*H_)              /* 524288 */
#define OUT_OFF_LW (OUT_OFF_P + B_*K_*H_) /* 655360 */

__device__ __forceinline__ unsigned short f2bf(float x) {
    unsigned int u = __float_as_uint(x);
    u += 0x7fffu + ((u >> 16) & 1u);   // RNE for finite inputs
    return (unsigned short)(u >> 16);
}
__device__ __forceinline__ float fast_tanh(float x) {
    float e = __expf(2.0f * x);
    return 1.0f - 2.0f * __builtin_amdgcn_rcpf(e + 1.0f);
}
__device__ __forceinline__ float fast_sigmoid(float x) {
    return __builtin_amdgcn_rcpf(1.0f + __expf(-x));
}
// Byte-offset XOR swizzles. Bits 4 AND 5 XOR'd from row bits 0..3 so that
// rows r and r+8 don't alias (256B/512B row strides are = 0 mod 32 banks).
// 16B alignment of b128 accesses preserved (bits 0..3 untouched).
__device__ __forceinline__ unsigned int swzbyte_p(unsigned int row, unsigned int col) { // [16][128] bf16
    unsigned int byte = row * 256u + col * 2u;
    return byte ^ ((row & 7u) << 4) ^ ((row & 8u) << 2);
}
__device__ __forceinline__ unsigned int swzbyte_b(unsigned int row, unsigned int pos) { // [16][256] bf16 (pos-space)
    unsigned int byte = row * 512u + pos * 2u;
    return byte ^ ((row & 7u) << 4) ^ ((row & 8u) << 2);
}

// raw barrier: LDS-visibility only; vmem (eps prefetch, atomics) stays in flight
#define BAR() do { asm volatile("s_waitcnt lgkmcnt(0)" ::: "memory"); \
                   __builtin_amdgcn_s_barrier(); \
                   __builtin_amdgcn_sched_barrier(0); } while (0)

#define MFMA16(a, bfrag, c) __builtin_amdgcn_mfma_f32_16x16x32_bf16((a), (bfrag), (c), 0, 0, 0)

__global__ __launch_bounds__(NTHR, 2) void pf_kernel(
    const float* __restrict__ x, const float* __restrict__ tspan,
    const float* __restrict__ eps, const float* __restrict__ Wb,
    const float* __restrict__ bb,
    const float* __restrict__ Wf1, const float* __restrict__ bf1,
    const float* __restrict__ Wf2, const float* __restrict__ bf2,
    const float* __restrict__ Wta, const float* __restrict__ bta,
    const float* __restrict__ Wtb, const float* __restrict__ btb,
    const float* __restrict__ nscale, float* __restrict__ out)
{
    const int tid  = threadIdx.x;
    const int lane = tid & 63;
    const int wv   = tid >> 6;        // wave 0..7
    const int ln15 = lane & 15;
    const int l4   = lane >> 4;
    const int bid  = blockIdx.x;      // 0..63
    const int b    = bid >> 2;
    const int k0   = (bid & 3) * KC;

    __shared__ unsigned short p_bf[KC * H_];     // particles bf16, swizzled (4KB)
    __shared__ unsigned short bbk_bf[KC * U_];   // backbone acts bf16, swizzled+col-permuted (8KB)
    __shared__ unsigned short x_bf[T_ * I_];     // whole x[b] pre-converted (32KB)
    __shared__ float ts_lds[T_];                 // (1KB)

    for (int i = tid; i < KC * H_; i += NTHR) p_bf[i] = 0;
    for (int i = tid; i < T_ * I_; i += NTHR) x_bf[i] = f2bf(x[b * (T_ * I_) + i]);
    for (int i = tid; i < T_; i += NTHR) ts_lds[i] = tspan[b * T_ + i];

    // ---- GEMM1 weights: wave owns bbk cols [wv*32, wv*32+32) ----
    short8 B1[6][2];
    #pragma unroll
    for (int kt = 0; kt < 6; ++kt) {
        #pragma unroll
        for (int ct = 0; ct < 2; ++ct) {
            short8 f;
            const int col = wv * 32 + ct * 16 + ln15;
            #pragma unroll
            for (int j = 0; j < 8; ++j) f[j] = (short)f2bf(Wb[(kt * 32 + l4 * 8 + j) * U_ + col]);
            B1[kt][ct] = f;
        }
    }
    float bias1[2];
    #pragma unroll
    for (int ct = 0; ct < 2; ++ct) bias1[ct] = bb[wv * 32 + ct * 16 + ln15];

    // ---- GEMM2 weights: wave owns h cols [wv*16, wv*16+16) for ALL 4 heads ----
    // bbk is stored column-PERMUTED within each 32-block: col c -> pos 2*(c&15)+(c>>4).
    // B-fragment element j corresponds to pos_local = l4*8+j, i.e. k_global =
    // kt*32 + (pos>>1) + ((pos&1)<<4). Contraction is invariant since A uses same order.
    const float* Whp[4] = {Wf1, Wf2, Wta, Wtb};
    const int hc = wv * 16 + ln15;
    short8 B2[4][8];
    #pragma unroll
    for (int hd = 0; hd < 4; ++hd) {
        #pragma unroll
        for (int kt = 0; kt < 8; ++kt) {
            short8 f;
            #pragma unroll
            for (int j = 0; j < 8; ++j) {
                const int pos = l4 * 8 + j;
                const int kg  = kt * 32 + (pos >> 1) + ((pos & 1) << 4);
                f[j] = (short)f2bf(Whp[hd][kg * H_ + hc]);
            }
            B2[hd][kt] = f;
        }
    }
    const float bf1c = bf1[hc], bf2c = bf2[hc];
    const float btac = bta[hc], btbc = btb[hc];
    const float nscc = nscale[hc];

    // pin fragments so the compiler can't rematerialize/sink the loads into the loop
    #pragma unroll
    for (int kt = 0; kt < 6; ++kt) asm volatile("" : "+v"(B1[kt][0]), "+v"(B1[kt][1]));
    #pragma unroll
    for (int hd = 0; hd < 4; ++hd) {
        #pragma unroll
        for (int kt = 0; kt < 8; ++kt) asm volatile("" : "+v"(B2[hd][kt]));
    }

    if ((bid & 3) == 0 && tid < K_)
        out[OUT_OFF_LW + b * K_ + tid] = -4.1588830833596715f; // -log(64)

    __syncthreads();   // full drain once: prologue LDS + global

    // eps lane base: ((t*B + b)*K + k0 + l4*4 + r)*H + hc
    const float* ep0 = eps + ((size_t)(b * K_ + k0 + l4 * 4)) * H_ + hc;
    float ecur[4];
    #pragma unroll
    for (int r = 0; r < 4; ++r) ecur[r] = ep0[r * H_];
    float tscur = ts_lds[0];

    const f32x4 zero4 = {0.f, 0.f, 0.f, 0.f};

    // x-part MFMAs for t=0 (accs carried into the loop's phase 1)
    f32x4 xacc0, xacc1;
    {
        const short8 ax0 = *(const short8*)&x_bf[0 * I_ + l4 * 8];
        const short8 ax1 = *(const short8*)&x_bf[0 * I_ + 32 + l4 * 8];
        xacc0 = MFMA16(ax0, B1[0][0], zero4); xacc1 = MFMA16(ax0, B1[0][1], zero4);
        xacc0 = MFMA16(ax1, B1[1][0], xacc0); xacc1 = MFMA16(ax1, B1[1][1], xacc1);
    }
    float psum_d = 0.f;   // deferred block-mean contribution (reduced one step late)

    #pragma unroll 1
    for (int t = 0; t < T_; ++t) {
        // ---- deferred reduce+atomic for step t-1 (overlaps this step's phase-1 latency) ----
        if (t) {
            float ps = psum_d;
            ps += __shfl_xor(ps, 16);
            ps += __shfl_xor(ps, 32);
            if (lane < 16)
                atomicAdd(&out[(size_t)(b * T_ + (t - 1)) * H_ + wv * 16 + lane], ps * (1.0f / 64.0f));
        }

        // ---- prefetch next-step inputs ----
        const int tn = (t + 1 < T_) ? t + 1 : t;
        const float* epn = ep0 + (size_t)tn * (B_ * K_ * H_);
        float enext[4];
        #pragma unroll
        for (int r = 0; r < 4; ++r) enext[r] = epn[r * H_];
        const float tsn = ts_lds[tn];

        // ---- phase 1: particle part of GEMM1 (x part already in xacc) ----
        f32x4 acc0 = xacc0, acc1 = xacc1;
        #pragma unroll
        for (int kt = 0; kt < 4; ++kt) {
            const short8 ap = *(const short8*)((const char*)p_bf + swzbyte_p(ln15, kt * 32 + l4 * 8));
            acc0 = MFMA16(ap, B1[2 + kt][0], acc0);
            acc1 = MFMA16(ap, B1[2 + kt][1], acc1);
        }
        #pragma unroll
        for (int r = 0; r < 4; ++r) {                 // C: row=(l>>4)*4+r, col=l&15
            const int row = l4 * 4 + r;
            const unsigned int p0 = f2bf(1.7159f * fast_tanh(0.666f * (acc0[r] + bias1[0])));
            const unsigned int p1 = f2bf(1.7159f * fast_tanh(0.666f * (acc1[r] + bias1[1])));
            // packed b32 write: cols (wv*32+ln15, wv*32+16+ln15) -> pos (2*ln15, 2*ln15+1)
            *(unsigned int*)((char*)bbk_bf + swzbyte_b(row, wv * 32 + 2 * ln15)) = p0 | (p1 << 16);
        }
        BAR();

        // ---- phase 2: GEMM2 (all 4 heads, own 16 h-cols) + in-register combine ----
        __builtin_amdgcn_s_setprio(1);
        f32x4 a_f1 = zero4, a_f2 = zero4, a_ta = zero4, a_tb = zero4;
        #pragma unroll
        for (int kt = 0; kt < 8; ++kt) {
            const short8 a = *(const short8*)((const char*)bbk_bf + swzbyte_b(ln15, kt * 32 + l4 * 8));
            a_f1 = MFMA16(a, B2[0][kt], a_f1);
            a_f2 = MFMA16(a, B2[1][kt], a_f2);
            a_ta = MFMA16(a, B2[2][kt], a_ta);
            a_tb = MFMA16(a, B2[3][kt], a_tb);
        }
        __builtin_amdgcn_s_setprio(0);

        const float sq = sqrtf(tscur);
        float psum = 0.f;
        const bool last = (t == T_ - 1);
        #pragma unroll
        for (int r = 0; r < 4; ++r) {
            const int row = l4 * 4 + r;
            const float f1v = fast_tanh(a_f1[r] + bf1c);
            const float f2v = fast_tanh(a_f2[r] + bf2c);
            const float tiv = fast_sigmoid((a_ta[r] + btac) * tscur + (a_tb[r] + btbc));
            const float np  = f1v + tiv * (f2v - f1v) + nscc * sq * ecur[r];
            *(unsigned short*)((char*)p_bf + swzbyte_p(row, hc)) = f2bf(np);
            psum += np;
            if (last)
                out[OUT_OFF_P + (size_t)(b * K_ + k0 + row) * H_ + hc] = np;
        }
        psum_d = psum;

        // ---- x-part MFMAs for step t+1 (independent of particle update; overlaps barrier) ----
        {
            const short8 axn0 = *(const short8*)&x_bf[tn * I_ + l4 * 8];
            const short8 axn1 = *(const short8*)&x_bf[tn * I_ + 32 + l4 * 8];
            xacc0 = MFMA16(axn0, B1[0][0], zero4); xacc1 = MFMA16(axn0, B1[0][1], zero4);
            xacc0 = MFMA16(axn1, B1[1][0], xacc0); xacc1 = MFMA16(axn1, B1[1][1], xacc1);
        }

        #pragma unroll
        for (int r = 0; r < 4; ++r) ecur[r] = enext[r];
        tscur = tsn;
        BAR();
    }

    // tail: reduce for t = T-1
    {
        float ps = psum_d;
        ps += __shfl_xor(ps, 16);
        ps += __shfl_xor(ps, 32);
        if (lane < 16)
            atomicAdd(&out[(size_t)(b * T_ + (T_ - 1)) * H_ + wv * 16 + lane], ps * (1.0f / 64.0f));
    }
}

extern "C" void kernel_launch(void* const* d_in, const int* in_sizes, int n_in,
                              void* d_out, int out_size, void* d_ws, size_t ws_size,
                              hipStream_t stream) {
    const float* x    = (const float*)d_in[0];
    const float* tsp  = (const float*)d_in[1];
    const float* eps  = (const float*)d_in[2];
    const float* Wb   = (const float*)d_in[3];
    const float* bb   = (const float*)d_in[4];
    const float* Wf1  = (const float*)d_in[5];
    const float* bf1  = (const float*)d_in[6];
    const float* Wf2  = (const float*)d_in[7];
    const float* bf2  = (const float*)d_in[8];
    const float* Wta  = (const float*)d_in[9];
    const float* bta  = (const float*)d_in[10];
    const float* Wtb  = (const float*)d_in[11];
    const float* btb  = (const float*)d_in[12];
    const float* nsc  = (const float*)d_in[13];
    float* out = (float*)d_out;

    // outputs region is accumulated with atomics -> zero every launch
    (void)hipMemsetAsync(d_out, 0, (size_t)OUT_OFF_P * sizeof(float), stream);
    pf_kernel<<<dim3(64), dim3(NTHR), 0, stream>>>(
        x, tsp, eps, Wb, bb, Wf1, bf1, Wf2, bf2, Wta, bta, Wtb, btb, nsc, out);
}